// Round 1
// baseline (136.696 us; speedup 1.0000x reference)
//
#include <hip/hip_runtime.h>

#define I_FEAT 256
#define O_FEAT 512
#define NSEG   8

// Fused LayerNorm + segment-gather + piecewise-linear projection.
// Block = 256 threads = 4 waves = 2 batch rows.
//   Phase 1: LN + seg index for the block's 2 rows -> LDS (xn, g*512 offsets)
//   Phase 2: wave w handles (row w>>1, output half w&1); lane owns 4 outputs
//            (float4); gather offset is wave-uniform (readfirstlane -> SGPR),
//            so each A/Bw load is one coalesced 1KB segment served by L1/L2.
__global__ __launch_bounds__(256) void kan_fused(
    const float* __restrict__ x,
    const float* __restrict__ Aw,
    const float* __restrict__ Bw,
    const float* __restrict__ gamma,
    const float* __restrict__ beta,
    float* __restrict__ out,
    int Bn)
{
    __shared__ float s_xn[2][I_FEAT];
    __shared__ int   s_off[2][I_FEAT];
    __shared__ float s_psum[4];
    __shared__ float s_psq[4];

    const int tid  = threadIdx.x;
    const int row0 = blockIdx.x * 2;
    const int wave = tid >> 6;

    // ---- Phase 1: LayerNorm + segment index (threads 0-127 -> row 0, 128-255 -> row 1)
    const int lr  = tid >> 7;
    const int lt  = tid & 127;
    const int row = row0 + lr;

    float v0 = 0.f, v1 = 0.f;
    if (row < Bn) {
        const float* xr = x + (size_t)row * I_FEAT;
        v0 = xr[lt];
        v1 = xr[lt + 128];
    }
    float sum = v0 + v1;
    float sq  = v0 * v0 + v1 * v1;
    #pragma unroll
    for (int d = 32; d > 0; d >>= 1) {
        sum += __shfl_down(sum, d);
        sq  += __shfl_down(sq, d);
    }
    if ((tid & 63) == 0) { s_psum[wave] = sum; s_psq[wave] = sq; }
    __syncthreads();

    {
        const float fsum = s_psum[2 * lr] + s_psum[2 * lr + 1];
        const float fsq  = s_psq[2 * lr]  + s_psq[2 * lr + 1];
        const float mu   = fsum * (1.0f / I_FEAT);
        const float var  = fsq * (1.0f / I_FEAT) - mu * mu;
        const float rs   = rsqrtf(var + 1e-5f);

        // feature lt
        {
            float xn = (v0 - mu) * rs * gamma[lt] + beta[lt];
            float fi = (xn + 1.0f) * 4.0f;       // (xn - GRID_MIN)/STEP, exact
            int seg = (int)fi;                    // trunc toward zero == jnp astype(int32)
            seg = seg < 0 ? 0 : (seg > NSEG - 1 ? NSEG - 1 : seg);
            s_xn[lr][lt]  = xn;
            s_off[lr][lt] = (lt * NSEG + seg) * O_FEAT;
        }
        // feature lt + 128
        {
            const int f = lt + 128;
            float xn = (v1 - mu) * rs * gamma[f] + beta[f];
            float fi = (xn + 1.0f) * 4.0f;
            int seg = (int)fi;
            seg = seg < 0 ? 0 : (seg > NSEG - 1 ? NSEG - 1 : seg);
            s_xn[lr][f]  = xn;
            s_off[lr][f] = (f * NSEG + seg) * O_FEAT;
        }
    }
    __syncthreads();

    // ---- Phase 2: gather-accumulate over the 256 features
    const int lane = tid & 63;
    const int lr2  = wave >> 1;
    const int row2 = row0 + lr2;
    if (row2 >= Bn) return;
    const int ob = ((wave & 1) << 8) | (lane << 2);   // output base for this lane

    float ax = 0.f, ay = 0.f, az = 0.f, aw = 0.f;     // xn * A accumulation
    float bx = 0.f, by = 0.f, bz = 0.f, bw = 0.f;     // Bw accumulation

    #pragma unroll 4
    for (int i = 0; i < I_FEAT; ++i) {
        const int   off = __builtin_amdgcn_readfirstlane(s_off[lr2][i]); // wave-uniform
        const float xn  = s_xn[lr2][i];
        const float4 a4 = *(const float4*)(Aw + off + ob);
        const float4 b4 = *(const float4*)(Bw + off + ob);
        ax = fmaf(xn, a4.x, ax); ay = fmaf(xn, a4.y, ay);
        az = fmaf(xn, a4.z, az); aw = fmaf(xn, a4.w, aw);
        bx += b4.x; by += b4.y; bz += b4.z; bw += b4.w;
    }

    float4 r;
    r.x = ax + bx; r.y = ay + by; r.z = az + bz; r.w = aw + bw;
    *(float4*)(out + (size_t)row2 * O_FEAT + ob) = r;
}

extern "C" void kernel_launch(void* const* d_in, const int* in_sizes, int n_in,
                              void* d_out, int out_size, void* d_ws, size_t ws_size,
                              hipStream_t stream) {
    const float* x    = (const float*)d_in[0];
    const float* Aw   = (const float*)d_in[1];
    const float* Bw   = (const float*)d_in[2];
    const float* gam  = (const float*)d_in[3];
    const float* bet  = (const float*)d_in[4];
    float* out        = (float*)d_out;

    const int Bn   = in_sizes[0] / I_FEAT;
    const int grid = (Bn + 1) / 2;
    hipLaunchKernelGGL(kan_fused, dim3(grid), dim3(256), 0, stream,
                       x, Aw, Bw, gam, bet, out, Bn);
}

// Round 2
// 105.376 us; speedup vs baseline: 1.2972x; 1.2972x over previous
//
#include <hip/hip_runtime.h>
#include <hip/hip_fp16.h>

#define I_FEAT 256
#define O_FEAT 512
#define NSEG   8

typedef __fp16 half2v __attribute__((ext_vector_type(2)));

#if __has_builtin(__builtin_amdgcn_fdot2)
#define FDOT2(a, b, c) __builtin_amdgcn_fdot2((a), (b), (c), false)
#else
static __device__ __forceinline__ float FDOT2(half2v a, half2v b, float c) {
    return c + (float)a[0] * (float)b[0] + (float)a[1] * (float)b[1];
}
#endif

static __device__ __forceinline__ uint32_t pack2(float a, float b) {
    half2v h = { (__fp16)a, (__fp16)b };
    return __builtin_bit_cast(uint32_t, h);
}

// Prologue: interleave A and Bw as f16 pairs: T[g*512 + o] = (half(A[g,o]), half(Bw[g,o])).
// 4 MB table -> fits a single XCD L2; halves gather demand vs fp32 A + fp32 B.
__global__ __launch_bounds__(256) void pack_weights(
    const float* __restrict__ Aw,
    const float* __restrict__ Bw,
    uint32_t* __restrict__ T, int n4)
{
    const int idx = blockIdx.x * 256 + threadIdx.x;
    if (idx >= n4) return;
    const float4 a = ((const float4*)Aw)[idx];
    const float4 b = ((const float4*)Bw)[idx];
    uint4 o;
    o.x = pack2(a.x, b.x);
    o.y = pack2(a.y, b.y);
    o.z = pack2(a.z, b.z);
    o.w = pack2(a.w, b.w);
    ((uint4*)T)[idx] = o;
}

// Fused LayerNorm + segment index + packed-f16 gather + dot2 accumulate.
// Block = 256 threads = 4 waves = 2 batch rows.
//   Phase 1: LN + seg -> LDS meta {packed half2(xn,1), table offset}
//   Phase 2: wave w -> (row w>>1, output half w&1); lane owns 4 outputs;
//            one dwordx4 gather per (row,i) delivers A and B for all 4 outputs,
//            consumed by v_dot2_f32_f16 (f32 accumulate).
__global__ __launch_bounds__(256) void kan_fused(
    const float* __restrict__ x,
    const uint32_t* __restrict__ T,
    const float* __restrict__ gamma,
    const float* __restrict__ beta,
    float* __restrict__ out,
    int Bn)
{
    __shared__ uint2 s_meta[2][I_FEAT];   // {pack2(xn,1), g*512}
    __shared__ float s_psum[4];
    __shared__ float s_psq[4];

    const int tid  = threadIdx.x;
    const int row0 = blockIdx.x * 2;
    const int wave = tid >> 6;

    // ---- Phase 1: LayerNorm + segment index (threads 0-127 -> row 0, 128-255 -> row 1)
    const int lr  = tid >> 7;
    const int lt  = tid & 127;
    const int row = row0 + lr;

    float v0 = 0.f, v1 = 0.f;
    if (row < Bn) {
        const float* xr = x + (size_t)row * I_FEAT;
        v0 = xr[lt];
        v1 = xr[lt + 128];
    }
    float sum = v0 + v1;
    float sq  = v0 * v0 + v1 * v1;
    #pragma unroll
    for (int d = 32; d > 0; d >>= 1) {
        sum += __shfl_down(sum, d);
        sq  += __shfl_down(sq, d);
    }
    if ((tid & 63) == 0) { s_psum[wave] = sum; s_psq[wave] = sq; }
    __syncthreads();

    {
        const float fsum = s_psum[2 * lr] + s_psum[2 * lr + 1];
        const float fsq  = s_psq[2 * lr]  + s_psq[2 * lr + 1];
        const float mu   = fsum * (1.0f / I_FEAT);
        const float var  = fsq * (1.0f / I_FEAT) - mu * mu;
        const float rs   = rsqrtf(var + 1e-5f);

        // feature lt
        {
            float xn = (v0 - mu) * rs * gamma[lt] + beta[lt];
            float fi = (xn + 1.0f) * 4.0f;        // (xn - GRID_MIN)/STEP in fp32 (exact seg match)
            int seg = (int)fi;                     // trunc == jnp astype(int32)
            seg = seg < 0 ? 0 : (seg > NSEG - 1 ? NSEG - 1 : seg);
            s_meta[lr][lt] = make_uint2(pack2(xn, 1.0f),
                                        (uint32_t)((lt * NSEG + seg) * O_FEAT));
        }
        // feature lt + 128
        {
            const int f = lt + 128;
            float xn = (v1 - mu) * rs * gamma[f] + beta[f];
            float fi = (xn + 1.0f) * 4.0f;
            int seg = (int)fi;
            seg = seg < 0 ? 0 : (seg > NSEG - 1 ? NSEG - 1 : seg);
            s_meta[lr][f] = make_uint2(pack2(xn, 1.0f),
                                       (uint32_t)((f * NSEG + seg) * O_FEAT));
        }
    }
    __syncthreads();

    // ---- Phase 2: packed gather-accumulate over the 256 features
    const int lane = tid & 63;
    const int lr2  = wave >> 1;
    const int row2 = row0 + lr2;
    if (row2 >= Bn) return;
    const int ob = ((wave & 1) << 8) | (lane << 2);   // output base for this lane

    float ax = 0.f, ay = 0.f, az = 0.f, aw = 0.f;

    #pragma unroll 8
    for (int i = 0; i < I_FEAT; ++i) {
        const uint2 meta = s_meta[lr2][i];            // LDS broadcast (same addr all lanes)
        const int   off  = __builtin_amdgcn_readfirstlane((int)meta.y);
        const half2v xv  = __builtin_bit_cast(half2v, meta.x);
        const uint4 t = *(const uint4*)(T + off + ob);
        ax = FDOT2(xv, __builtin_bit_cast(half2v, t.x), ax);
        ay = FDOT2(xv, __builtin_bit_cast(half2v, t.y), ay);
        az = FDOT2(xv, __builtin_bit_cast(half2v, t.z), az);
        aw = FDOT2(xv, __builtin_bit_cast(half2v, t.w), aw);
    }

    float4 r; r.x = ax; r.y = ay; r.z = az; r.w = aw;
    *(float4*)(out + (size_t)row2 * O_FEAT + ob) = r;
}

extern "C" void kernel_launch(void* const* d_in, const int* in_sizes, int n_in,
                              void* d_out, int out_size, void* d_ws, size_t ws_size,
                              hipStream_t stream) {
    const float* x    = (const float*)d_in[0];
    const float* Aw   = (const float*)d_in[1];
    const float* Bw   = (const float*)d_in[2];
    const float* gam  = (const float*)d_in[3];
    const float* bet  = (const float*)d_in[4];
    float* out        = (float*)d_out;
    uint32_t* T       = (uint32_t*)d_ws;              // 2048*512*4B = 4 MB

    const int Bn = in_sizes[0] / I_FEAT;

    const int n4 = (I_FEAT * NSEG * O_FEAT) / 4;      // 262144 float4 groups
    hipLaunchKernelGGL(pack_weights, dim3((n4 + 255) / 256), dim3(256), 0, stream,
                       Aw, Bw, T, n4);

    const int grid = (Bn + 1) / 2;
    hipLaunchKernelGGL(kan_fused, dim3(grid), dim3(256), 0, stream,
                       x, T, gam, bet, out, Bn);
}